// Round 2
// baseline (597.551 us; speedup 1.0000x reference)
//
#include <hip/hip_runtime.h>
#include <math.h>

#define BATCH 48
#define HH 128
#define WW 128
#define HW (128*128)
#define SZ (48*16*HW)          // 12,582,912 floats per 16-ch feature map
#define EPS 1e-5f

__device__ __forceinline__ float mishf(float v) {
    float sp = log1pf(__expf(v));      // overflow -> inf -> tanh=1 -> v (correct limit)
    return v * tanhf(sp);
}

// ---------------- K1: 1x1 conv 32->16 (high_fea -> in0) ----------------
__global__ __launch_bounds__(256) void k_c0(const float* __restrict__ x,
                                            const float* __restrict__ W,
                                            float* __restrict__ out) {
    __shared__ float w[16*32];
    int tid = threadIdx.x;
    for (int i = tid; i < 512; i += 256) w[i] = W[i];
    __syncthreads();
    int g = blockIdx.x * 256 + tid;          // 4-pixel group index
    int b = g >> 12;                         // 4096 groups per batch
    int off = (g & 4095) << 2;
    const float* xb = x + (size_t)b * 32 * HW + off;
    float acc[16][4];
    #pragma unroll
    for (int c = 0; c < 16; ++c) { acc[c][0]=acc[c][1]=acc[c][2]=acc[c][3]=0.f; }
    #pragma unroll 4
    for (int ci = 0; ci < 32; ++ci) {
        float4 xv = *(const float4*)(xb + (size_t)ci * HW);
        #pragma unroll
        for (int co = 0; co < 16; ++co) {
            float wv = w[co*32 + ci];
            acc[co][0] += wv*xv.x; acc[co][1] += wv*xv.y;
            acc[co][2] += wv*xv.z; acc[co][3] += wv*xv.w;
        }
    }
    float* ob = out + (size_t)b * 16 * HW + off;
    #pragma unroll
    for (int co = 0; co < 16; ++co)
        *(float4*)(ob + (size_t)co * HW) = make_float4(acc[co][0],acc[co][1],acc[co][2],acc[co][3]);
}

// ------------- shared helpers for tiled 3x3 convs -------------
// Tile: 64 wide x 8 tall outputs per 128-thread block.
// LDS window per channel: 12 rows x 68 cols (halo 2 each side vertically and horizontally).
// Row r of window = global row y0-2+r; col c = global col x0-2+c.
#define TROWS 12
#define TCOLS 68
#define TSZ (TROWS*TCOLS)

__device__ __forceinline__ void stage_rows(const float* __restrict__ src, float* __restrict__ dst,
                                           int b, int c, int y0, int x0, int tid,
                                           int r0, int r1) {
    const float* p = src + (size_t)(b*16 + c) * HW;
    for (int i = tid + r0*TCOLS; i < r1*TCOLS; i += 128) {
        int r = i / TCOLS, cc = i - r*TCOLS;
        int gy = y0 - 2 + r, gx = x0 - 2 + cc;
        float v = 0.f;
        if ((unsigned)gy < 128u && (unsigned)gx < 128u) v = p[gy*WW + gx];
        dst[i] = v;
    }
}

// 8 output channels, dilation D, accumulate into acc[COBASE..COBASE+7]
template<int D, int COBASE>
__device__ __forceinline__ void conv_step8(const float* __restrict__ sb, const float* __restrict__ w,
                                           int tx, int ty, float (&acc)[16][4]) {
    #pragma unroll
    for (int ky = 0; ky < 3; ++ky) {
        const float* rp = sb + (ty + 2 + D*(ky-1))*TCOLS + tx*4;
        float4 lo = *(const float4*)rp;
        float4 hi = *(const float4*)(rp + 4);
        float u[8] = {lo.x,lo.y,lo.z,lo.w,hi.x,hi.y,hi.z,hi.w};
        #pragma unroll
        for (int kx = 0; kx < 3; ++kx) {
            float4 w0 = *(const float4*)(w + ky*24 + kx*8);
            float4 w1 = *(const float4*)(w + ky*24 + kx*8 + 4);
            #pragma unroll
            for (int j = 0; j < 4; ++j) {
                float v = u[2 - D + D*kx + j];
                acc[COBASE+0][j] += w0.x*v; acc[COBASE+1][j] += w0.y*v;
                acc[COBASE+2][j] += w0.z*v; acc[COBASE+3][j] += w0.w*v;
                acc[COBASE+4][j] += w1.x*v; acc[COBASE+5][j] += w1.y*v;
                acc[COBASE+6][j] += w1.z*v; acc[COBASE+7][j] += w1.w*v;
            }
        }
    }
}

// ---------------- K2: dual-branch 3x3 (dil1 ch0-7, dil2 ch8-15) + GN(groups=1) stats ----------------
__global__ __launch_bounds__(128) void k_branch(const float* __restrict__ in0,
                                                const float* __restrict__ Wc1,
                                                const float* __restrict__ Wc2,
                                                float* __restrict__ outp,
                                                float* __restrict__ stat) {
    __shared__ float buf[2][TSZ];
    __shared__ float wT[2*576];             // [branch][ci][ky][kx][co]
    int tid = threadIdx.x;
    for (int i = tid; i < 576; i += 128) {
        int co = i & 7; int t = i >> 3; int kyx = t % 9; int ci = t / 9;
        wT[i]       = Wc1[(co*8 + ci)*9 + kyx];
        wT[576 + i] = Wc2[(co*8 + ci)*9 + kyx];
    }
    int b = blockIdx.z;
    int x0 = blockIdx.x * 64, y0 = blockIdx.y * 8;
    int tx = tid & 15, ty = tid >> 4;       // tx: 16 x-groups of 4 px, ty: 8 rows
    float acc[16][4];
    #pragma unroll
    for (int c = 0; c < 16; ++c) { acc[c][0]=acc[c][1]=acc[c][2]=acc[c][3]=0.f; }

    stage_rows(in0, buf[0], b, 0, y0, x0, tid, 1, 11);   // dil1 needs rows 1..10
    for (int ci = 0; ci < 8; ++ci) {
        __syncthreads();
        if (ci < 7)  stage_rows(in0, buf[(ci+1)&1], b, ci+1, y0, x0, tid, 1, 11);
        else         stage_rows(in0, buf[(ci+1)&1], b, ci+1, y0, x0, tid, 0, 12);
        conv_step8<1,0>(buf[ci&1], wT + ci*72, tx, ty, acc);
    }
    for (int ci = 8; ci < 16; ++ci) {
        __syncthreads();
        if (ci < 15) stage_rows(in0, buf[(ci+1)&1], b, ci+1, y0, x0, tid, 0, 12);  // dil2: rows 0..11
        conv_step8<2,8>(buf[ci&1], wT + 576 + (ci-8)*72, tx, ty, acc);
    }

    float s = 0.f, q = 0.f;
    float* ob = outp + (size_t)b*16*HW + (y0+ty)*WW + x0 + tx*4;
    #pragma unroll
    for (int c = 0; c < 16; ++c) {
        *(float4*)(ob + (size_t)c*HW) = make_float4(acc[c][0],acc[c][1],acc[c][2],acc[c][3]);
        #pragma unroll
        for (int j = 0; j < 4; ++j) { s += acc[c][j]; q += acc[c][j]*acc[c][j]; }
    }
    #pragma unroll
    for (int o = 32; o > 0; o >>= 1) { s += __shfl_down(s,o); q += __shfl_down(q,o); }
    if ((tid & 63) == 0) { atomicAdd(&stat[b*2], s); atomicAdd(&stat[b*2+1], q); }
}

// ---------------- K3: 1x1 conv 24->16 (low) + GN(groups=2) stats ----------------
__global__ __launch_bounds__(256) void k_low(const float* __restrict__ x,
                                             const float* __restrict__ W,
                                             float* __restrict__ outp,
                                             float* __restrict__ stat) {
    __shared__ float w[16*24];
    int tid = threadIdx.x;
    for (int i = tid; i < 384; i += 256) w[i] = W[i];
    __syncthreads();
    int g = blockIdx.x * 256 + tid;
    int b = g >> 12; int off = (g & 4095) << 2;
    const float* xb = x + (size_t)b * 24 * HW + off;
    float acc[16][4];
    #pragma unroll
    for (int c = 0; c < 16; ++c) { acc[c][0]=acc[c][1]=acc[c][2]=acc[c][3]=0.f; }
    #pragma unroll 4
    for (int ci = 0; ci < 24; ++ci) {
        float4 xv = *(const float4*)(xb + (size_t)ci * HW);
        #pragma unroll
        for (int co = 0; co < 16; ++co) {
            float wv = w[co*24 + ci];
            acc[co][0] += wv*xv.x; acc[co][1] += wv*xv.y;
            acc[co][2] += wv*xv.z; acc[co][3] += wv*xv.w;
        }
    }
    float* ob = outp + (size_t)b * 16 * HW + off;
    float s0=0.f,q0=0.f,s1=0.f,q1=0.f;
    #pragma unroll
    for (int co = 0; co < 16; ++co) {
        *(float4*)(ob + (size_t)co * HW) = make_float4(acc[co][0],acc[co][1],acc[co][2],acc[co][3]);
        #pragma unroll
        for (int j = 0; j < 4; ++j) {
            if (co < 8) { s0 += acc[co][j]; q0 += acc[co][j]*acc[co][j]; }
            else        { s1 += acc[co][j]; q1 += acc[co][j]*acc[co][j]; }
        }
    }
    #pragma unroll
    for (int o = 32; o > 0; o >>= 1) {
        s0 += __shfl_down(s0,o); q0 += __shfl_down(q0,o);
        s1 += __shfl_down(s1,o); q1 += __shfl_down(q1,o);
    }
    if ((tid & 63) == 0) {
        atomicAdd(&stat[b*4+0], s0); atomicAdd(&stat[b*4+1], q0);
        atomicAdd(&stat[b*4+2], s1); atomicAdd(&stat[b*4+3], q1);
    }
}

// ---------------- K4: GN-apply (high & low) + add + mish ----------------
__global__ __launch_bounds__(256) void k_fuse(const float* __restrict__ hp, const float* __restrict__ lp,
                                              const float* __restrict__ gbn, const float* __restrict__ bbn,
                                              const float* __restrict__ glow, const float* __restrict__ blow,
                                              const float* __restrict__ sh, const float* __restrict__ sl,
                                              float* __restrict__ r) {
    int i4 = blockIdx.x * 256 + threadIdx.x;
    int p = i4 << 2;
    int b = p >> 18;                 // / (16*HW)
    int rem = p & 262143;
    int c = rem >> 14;               // / HW
    float muh = sh[b*2] * (1.f/262144.f);
    float varh = sh[b*2+1]*(1.f/262144.f) - muh*muh;
    float rsh = rsqrtf(varh + EPS);
    int gi = b*4 + (c>>3)*2;
    float mul = sl[gi] * (1.f/131072.f);
    float varl = sl[gi+1]*(1.f/131072.f) - mul*mul;
    float rsl = rsqrtf(varl + EPS);
    float ga = gbn[c]*rsh, bh = bbn[c] - muh*ga;
    float gl = glow[c]*rsl, bl = blow[c] - mul*gl;
    float4 h = *(const float4*)(hp + (size_t)p);
    float4 l = *(const float4*)(lp + (size_t)p);
    float4 o;
    o.x = mishf(h.x*ga + bh + l.x*gl + bl);
    o.y = mishf(h.y*ga + bh + l.y*gl + bl);
    o.z = mishf(h.z*ga + bh + l.z*gl + bl);
    o.w = mishf(h.w*ga + bh + l.w*gl + bl);
    *(float4*)(r + (size_t)p) = o;
}

// ---------------- K5: 3x3 conv 16->16 pad1 + GN(groups=2) stats ----------------
__global__ __launch_bounds__(128) void k_ref(const float* __restrict__ rin,
                                             const float* __restrict__ Wref,
                                             float* __restrict__ outp,
                                             float* __restrict__ stat) {
    __shared__ float buf[2][TSZ];
    __shared__ float wT[16*144];            // [ci][ky][kx][co16]
    int tid = threadIdx.x;
    for (int i = tid; i < 2304; i += 128) {
        int co = i & 15; int t = i >> 4; int kyx = t % 9; int ci = t / 9;
        wT[i] = Wref[(co*16 + ci)*9 + kyx];
    }
    int b = blockIdx.z;
    int x0 = blockIdx.x * 64, y0 = blockIdx.y * 8;
    int tx = tid & 15, ty = tid >> 4;
    float acc[16][4];
    #pragma unroll
    for (int c = 0; c < 16; ++c) { acc[c][0]=acc[c][1]=acc[c][2]=acc[c][3]=0.f; }

    stage_rows(rin, buf[0], b, 0, y0, x0, tid, 1, 11);   // dil1: rows 1..10 only
    for (int ci = 0; ci < 16; ++ci) {
        __syncthreads();
        if (ci < 15) stage_rows(rin, buf[(ci+1)&1], b, ci+1, y0, x0, tid, 1, 11);
        const float* sb = buf[ci&1];
        const float* w = wT + ci*144;
        #pragma unroll
        for (int ky = 0; ky < 3; ++ky) {
            const float* rp = sb + (ty + 2 + (ky-1))*TCOLS + tx*4;
            float4 lo = *(const float4*)rp;
            float4 hi = *(const float4*)(rp + 4);
            float u[8] = {lo.x,lo.y,lo.z,lo.w,hi.x,hi.y,hi.z,hi.w};
            #pragma unroll
            for (int kx = 0; kx < 3; ++kx) {
                const float* wp = w + ky*48 + kx*16;
                float4 wa = *(const float4*)wp;
                float4 wb = *(const float4*)(wp+4);
                float4 wc = *(const float4*)(wp+8);
                float4 wd = *(const float4*)(wp+12);
                float wr[16] = {wa.x,wa.y,wa.z,wa.w, wb.x,wb.y,wb.z,wb.w,
                                wc.x,wc.y,wc.z,wc.w, wd.x,wd.y,wd.z,wd.w};
                #pragma unroll
                for (int j = 0; j < 4; ++j) {
                    float v = u[1 + kx + j];
                    #pragma unroll
                    for (int c = 0; c < 16; ++c) acc[c][j] += wr[c]*v;
                }
            }
        }
    }

    float s0=0.f,q0=0.f,s1=0.f,q1=0.f;
    float* ob = outp + (size_t)b*16*HW + (y0+ty)*WW + x0 + tx*4;
    #pragma unroll
    for (int c = 0; c < 16; ++c) {
        *(float4*)(ob + (size_t)c*HW) = make_float4(acc[c][0],acc[c][1],acc[c][2],acc[c][3]);
        #pragma unroll
        for (int j = 0; j < 4; ++j) {
            if (c < 8) { s0 += acc[c][j]; q0 += acc[c][j]*acc[c][j]; }
            else       { s1 += acc[c][j]; q1 += acc[c][j]*acc[c][j]; }
        }
    }
    #pragma unroll
    for (int o = 32; o > 0; o >>= 1) {
        s0 += __shfl_down(s0,o); q0 += __shfl_down(q0,o);
        s1 += __shfl_down(s1,o); q1 += __shfl_down(q1,o);
    }
    if ((tid & 63) == 0) {
        atomicAdd(&stat[b*4+0], s0); atomicAdd(&stat[b*4+1], q0);
        atomicAdd(&stat[b*4+2], s1); atomicAdd(&stat[b*4+3], q1);
    }
}

// ---------------- K6: GN-apply + mish + 1x1 seg conv 16->1 ----------------
__global__ __launch_bounds__(256) void k_seg(const float* __restrict__ rp,
                                             const float* __restrict__ gref, const float* __restrict__ bref,
                                             const float* __restrict__ wseg, const float* __restrict__ sr,
                                             float* __restrict__ seg) {
    int i4 = blockIdx.x * 256 + threadIdx.x;    // 196608 total
    int b = i4 >> 12; int off = (i4 & 4095) << 2;
    const float* pb = rp + (size_t)b*16*HW + off;
    float ax=0.f, ay=0.f, az=0.f, aw=0.f;
    #pragma unroll
    for (int c = 0; c < 16; ++c) {
        int gi = b*4 + (c>>3)*2;
        float mu = sr[gi] * (1.f/131072.f);
        float var = sr[gi+1]*(1.f/131072.f) - mu*mu;
        float rs = rsqrtf(var + EPS);
        float ga = gref[c]*rs, bb = bref[c] - mu*ga;
        float wv = wseg[c];
        float4 v = *(const float4*)(pb + (size_t)c*HW);
        ax += wv*mishf(v.x*ga + bb);
        ay += wv*mishf(v.y*ga + bb);
        az += wv*mishf(v.z*ga + bb);
        aw += wv*mishf(v.w*ga + bb);
    }
    *(float4*)(seg + (size_t)b*HW + off) = make_float4(ax,ay,az,aw);
}

// ---------------- K7: bilinear x4 upsample + sigmoid ----------------
__global__ __launch_bounds__(256) void k_up(const float* __restrict__ seg, float* __restrict__ out) {
    int i4 = blockIdx.x * 256 + threadIdx.x;    // 3,145,728 total
    int b = i4 / (512*128);
    int rem = i4 - b*(512*128);
    int y = rem >> 7; int k = rem & 127;
    const float* sp = seg + (size_t)b * HW;
    float fy = fminf(fmaxf(0.25f*y - 0.375f, 0.f), 127.f);
    int y0 = min((int)fy, 126);
    float wy = fy - (float)y0;
    const float* r0 = sp + y0*WW;
    const float* r1 = r0 + WW;
    float res[4];
    #pragma unroll
    for (int j = 0; j < 4; ++j) {
        int x = k*4 + j;
        float fx = fminf(fmaxf(0.25f*x - 0.375f, 0.f), 127.f);
        int x0 = min((int)fx, 126);
        float wx = fx - (float)x0;
        float v0 = r0[x0]*(1.f-wx) + r0[x0+1]*wx;
        float v1 = r1[x0]*(1.f-wx) + r1[x0+1]*wx;
        float v = v0*(1.f-wy) + v1*wy;
        res[j] = 1.f/(1.f + __expf(-v));
    }
    *(float4*)(out + (size_t)i4*4) = make_float4(res[0],res[1],res[2],res[3]);
}

extern "C" void kernel_launch(void* const* d_in, const int* in_sizes, int n_in,
                              void* d_out, int out_size, void* d_ws, size_t ws_size,
                              hipStream_t stream) {
    const float* low  = (const float*)d_in[0];
    const float* high = (const float*)d_in[1];
    const float* Wc0  = (const float*)d_in[2];
    const float* Wc1  = (const float*)d_in[3];
    const float* Wc2  = (const float*)d_in[4];
    const float* gbn  = (const float*)d_in[5];
    const float* bbn  = (const float*)d_in[6];
    const float* Wlow = (const float*)d_in[7];
    const float* glow = (const float*)d_in[8];
    const float* blow = (const float*)d_in[9];
    const float* Wref = (const float*)d_in[10];
    const float* gref = (const float*)d_in[11];
    const float* bref = (const float*)d_in[12];
    const float* Wseg = (const float*)d_in[13];

    float* ws = (float*)d_ws;
    float* A  = ws;                        // in0, later r
    float* Bb = ws + (size_t)SZ;           // high_pre, later ref_pre
    float* C  = ws + 2*(size_t)SZ;         // low_pre
    float* D  = ws + 3*(size_t)SZ;         // seg (48*16384)
    float* ST = D + (size_t)48*HW;         // stats: 480 floats (zeroed each launch)

    hipMemsetAsync(ST, 0, 480*sizeof(float), stream);

    k_c0    <<<768, 256, 0, stream>>>(high, Wc0, A);
    k_branch<<<dim3(2,16,48), 128, 0, stream>>>(A, Wc1, Wc2, Bb, ST);
    k_low   <<<768, 256, 0, stream>>>(low, Wlow, C, ST + 96);
    k_fuse  <<<12288, 256, 0, stream>>>(Bb, C, gbn, bbn, glow, blow, ST, ST + 96, A);
    k_ref   <<<dim3(2,16,48), 128, 0, stream>>>(A, Wref, Bb, ST + 288);
    k_seg   <<<768, 256, 0, stream>>>(Bb, gref, bref, Wseg, ST + 288, D);
    k_up    <<<12288, 256, 0, stream>>>(D, (float*)d_out);
}

// Round 3
// 563.716 us; speedup vs baseline: 1.0600x; 1.0600x over previous
//
#include <hip/hip_runtime.h>
#include <math.h>

#define BATCH 48
#define HH 128
#define WW 128
#define HW (128*128)
#define SZ (48*16*HW)          // 12,582,912 floats per 16-ch feature map
#define EPS 1e-5f

__device__ __forceinline__ float mishf(float v) {
    float sp = log1pf(__expf(v));      // overflow -> inf -> tanh=1 -> v (correct limit)
    return v * tanhf(sp);
}

// ---------------- K1: 1x1 conv 32->16 (high_fea -> in0) + weight transposes ----------------
// Block 0 additionally transposes Wc1/Wc2/Wref into [ci][kyx][co8] layout so the
// conv kernels can read weights with wave-uniform indices (s_load, SGPR operands).
__global__ __launch_bounds__(256) void k_c0(const float* __restrict__ x,
                                            const float* __restrict__ W,
                                            const float* __restrict__ Wc1,
                                            const float* __restrict__ Wc2,
                                            const float* __restrict__ Wref,
                                            float* __restrict__ WTb,   // 1152 floats
                                            float* __restrict__ WTr,   // 2304 floats
                                            float* __restrict__ out) {
    __shared__ float w[16*32];
    int tid = threadIdx.x;
    for (int i = tid; i < 512; i += 256) w[i] = W[i];
    if (blockIdx.x == 0) {
        for (int i = tid; i < 576; i += 256) {
            int co = i & 7; int t = i >> 3; int kyx = t % 9; int ci = t / 9;
            WTb[(ci*9 + kyx)*8 + co]       = Wc1[(co*8 + ci)*9 + kyx];
            WTb[576 + (ci*9 + kyx)*8 + co] = Wc2[(co*8 + ci)*9 + kyx];
        }
        for (int i = tid; i < 2304; i += 256) {
            int co = i & 7; int t = i >> 3; int kyx = t % 9; int cih = t / 9;  // 0..31
            int ci = cih & 15; int h = cih >> 4;
            WTr[((h*16 + ci)*9 + kyx)*8 + co] = Wref[((h*8 + co)*16 + ci)*9 + kyx];
        }
    }
    __syncthreads();
    int g = blockIdx.x * 256 + tid;          // 4-pixel group index
    int b = g >> 12;                         // 4096 groups per batch
    int off = (g & 4095) << 2;
    const float* xb = x + (size_t)b * 32 * HW + off;
    float acc[16][4];
    #pragma unroll
    for (int c = 0; c < 16; ++c) { acc[c][0]=acc[c][1]=acc[c][2]=acc[c][3]=0.f; }
    #pragma unroll 4
    for (int ci = 0; ci < 32; ++ci) {
        float4 xv = *(const float4*)(xb + (size_t)ci * HW);
        #pragma unroll
        for (int co = 0; co < 16; ++co) {
            float wv = w[co*32 + ci];
            acc[co][0] += wv*xv.x; acc[co][1] += wv*xv.y;
            acc[co][2] += wv*xv.z; acc[co][3] += wv*xv.w;
        }
    }
    float* ob = out + (size_t)b * 16 * HW + off;
    #pragma unroll
    for (int co = 0; co < 16; ++co)
        *(float4*)(ob + (size_t)co * HW) = make_float4(acc[co][0],acc[co][1],acc[co][2],acc[co][3]);
}

// ------------- shared helpers for tiled 3x3 convs -------------
// Tile: 64 wide x 8 tall outputs per 128-thread block.
// LDS window per channel: 12 rows x 68 cols; row r = global row y0-2+r, col c = x0-2+c.
#define TROWS 12
#define TCOLS 68
#define TSZ (TROWS*TCOLS)

__device__ __forceinline__ void stage_rows(const float* __restrict__ src, float* __restrict__ dst,
                                           int b, int c, int y0, int x0, int tid,
                                           int r0, int r1) {
    const float* p = src + (size_t)(b*16 + c) * HW;
    for (int i = tid + r0*TCOLS; i < r1*TCOLS; i += 128) {
        int r = i / TCOLS, cc = i - r*TCOLS;
        int gy = y0 - 2 + r, gx = x0 - 2 + cc;
        float v = 0.f;
        if ((unsigned)gy < 128u && (unsigned)gx < 128u) v = p[gy*WW + gx];
        dst[i] = v;
    }
}

// 8 output channels, dilation D. Weights wt: 72 floats [kyx][co8], read with
// wave-uniform indices -> scalar loads into SGPRs.
template<int D>
__device__ __forceinline__ void conv8(const float* __restrict__ sb, const float* __restrict__ wt,
                                      int tx, int ty, float (&acc)[8][4]) {
    #pragma unroll
    for (int ky = 0; ky < 3; ++ky) {
        const float* rp = sb + (ty + 2 + D*(ky-1))*TCOLS + tx*4;
        float4 lo = *(const float4*)rp;
        float4 hi = *(const float4*)(rp + 4);
        float u[8] = {lo.x,lo.y,lo.z,lo.w,hi.x,hi.y,hi.z,hi.w};
        #pragma unroll
        for (int kx = 0; kx < 3; ++kx) {
            const float* wp = wt + (ky*3 + kx)*8;
            float w0 = wp[0], w1 = wp[1], w2 = wp[2], w3 = wp[3];
            float w4 = wp[4], w5 = wp[5], w6 = wp[6], w7 = wp[7];
            #pragma unroll
            for (int j = 0; j < 4; ++j) {
                float v = u[2 - D + D*kx + j];
                acc[0][j] += w0*v; acc[1][j] += w1*v;
                acc[2][j] += w2*v; acc[3][j] += w3*v;
                acc[4][j] += w4*v; acc[5][j] += w5*v;
                acc[6][j] += w6*v; acc[7][j] += w7*v;
            }
        }
    }
}

// ---------------- K2: dual-branch 3x3; blockIdx.z = b*2 + branch ----------------
// branch 0: dil1, in ch 0-7, out ch 0-7; branch 1: dil2, in ch 8-15, out ch 8-15.
__global__ __launch_bounds__(128) void k_branch(const float* __restrict__ in0,
                                                const float* __restrict__ WTb,
                                                float* __restrict__ outp,
                                                float* __restrict__ stat) {
    __shared__ float buf[2][TSZ];
    int tid = threadIdx.x;
    int bz = blockIdx.z; int b = bz >> 1; int br = bz & 1;
    int x0 = blockIdx.x * 64, y0 = blockIdx.y * 8;
    int tx = tid & 15, ty = tid >> 4;
    float acc[8][4];
    #pragma unroll
    for (int c = 0; c < 8; ++c) { acc[c][0]=acc[c][1]=acc[c][2]=acc[c][3]=0.f; }
    const float* wb = WTb + br*576;
    int c0 = br*8;
    int r0 = br ? 0 : 1, r1 = br ? 12 : 11;

    stage_rows(in0, buf[0], b, c0, y0, x0, tid, r0, r1);
    if (br == 0) {
        for (int ci = 0; ci < 8; ++ci) {
            __syncthreads();
            if (ci < 7) stage_rows(in0, buf[(ci+1)&1], b, c0+ci+1, y0, x0, tid, r0, r1);
            conv8<1>(buf[ci&1], wb + ci*72, tx, ty, acc);
        }
    } else {
        for (int ci = 0; ci < 8; ++ci) {
            __syncthreads();
            if (ci < 7) stage_rows(in0, buf[(ci+1)&1], b, c0+ci+1, y0, x0, tid, r0, r1);
            conv8<2>(buf[ci&1], wb + ci*72, tx, ty, acc);
        }
    }

    float s = 0.f, q = 0.f;
    float* ob = outp + (size_t)(b*16 + c0)*HW + (y0+ty)*WW + x0 + tx*4;
    #pragma unroll
    for (int c = 0; c < 8; ++c) {
        *(float4*)(ob + (size_t)c*HW) = make_float4(acc[c][0],acc[c][1],acc[c][2],acc[c][3]);
        #pragma unroll
        for (int j = 0; j < 4; ++j) { s += acc[c][j]; q += acc[c][j]*acc[c][j]; }
    }
    #pragma unroll
    for (int o = 32; o > 0; o >>= 1) { s += __shfl_down(s,o); q += __shfl_down(q,o); }
    if ((tid & 63) == 0) { atomicAdd(&stat[b*2], s); atomicAdd(&stat[b*2+1], q); }
}

// ---------------- K3: 1x1 conv 24->16 (low) + GN(groups=2) stats ----------------
__global__ __launch_bounds__(256) void k_low(const float* __restrict__ x,
                                             const float* __restrict__ W,
                                             float* __restrict__ outp,
                                             float* __restrict__ stat) {
    __shared__ float w[16*24];
    int tid = threadIdx.x;
    for (int i = tid; i < 384; i += 256) w[i] = W[i];
    __syncthreads();
    int g = blockIdx.x * 256 + tid;
    int b = g >> 12; int off = (g & 4095) << 2;
    const float* xb = x + (size_t)b * 24 * HW + off;
    float acc[16][4];
    #pragma unroll
    for (int c = 0; c < 16; ++c) { acc[c][0]=acc[c][1]=acc[c][2]=acc[c][3]=0.f; }
    #pragma unroll 4
    for (int ci = 0; ci < 24; ++ci) {
        float4 xv = *(const float4*)(xb + (size_t)ci * HW);
        #pragma unroll
        for (int co = 0; co < 16; ++co) {
            float wv = w[co*24 + ci];
            acc[co][0] += wv*xv.x; acc[co][1] += wv*xv.y;
            acc[co][2] += wv*xv.z; acc[co][3] += wv*xv.w;
        }
    }
    float* ob = outp + (size_t)b * 16 * HW + off;
    float s0=0.f,q0=0.f,s1=0.f,q1=0.f;
    #pragma unroll
    for (int co = 0; co < 16; ++co) {
        *(float4*)(ob + (size_t)co * HW) = make_float4(acc[co][0],acc[co][1],acc[co][2],acc[co][3]);
        #pragma unroll
        for (int j = 0; j < 4; ++j) {
            if (co < 8) { s0 += acc[co][j]; q0 += acc[co][j]*acc[co][j]; }
            else        { s1 += acc[co][j]; q1 += acc[co][j]*acc[co][j]; }
        }
    }
    #pragma unroll
    for (int o = 32; o > 0; o >>= 1) {
        s0 += __shfl_down(s0,o); q0 += __shfl_down(q0,o);
        s1 += __shfl_down(s1,o); q1 += __shfl_down(q1,o);
    }
    if ((tid & 63) == 0) {
        atomicAdd(&stat[b*4+0], s0); atomicAdd(&stat[b*4+1], q0);
        atomicAdd(&stat[b*4+2], s1); atomicAdd(&stat[b*4+3], q1);
    }
}

// ---------------- K4: GN-apply (high & low) + add + mish ----------------
__global__ __launch_bounds__(256) void k_fuse(const float* __restrict__ hp, const float* __restrict__ lp,
                                              const float* __restrict__ gbn, const float* __restrict__ bbn,
                                              const float* __restrict__ glow, const float* __restrict__ blow,
                                              const float* __restrict__ sh, const float* __restrict__ sl,
                                              float* __restrict__ r) {
    int i4 = blockIdx.x * 256 + threadIdx.x;
    int p = i4 << 2;
    int b = p >> 18;                 // / (16*HW)
    int rem = p & 262143;
    int c = rem >> 14;               // / HW
    float muh = sh[b*2] * (1.f/262144.f);
    float varh = sh[b*2+1]*(1.f/262144.f) - muh*muh;
    float rsh = rsqrtf(varh + EPS);
    int gi = b*4 + (c>>3)*2;
    float mul = sl[gi] * (1.f/131072.f);
    float varl = sl[gi+1]*(1.f/131072.f) - mul*mul;
    float rsl = rsqrtf(varl + EPS);
    float ga = gbn[c]*rsh, bh = bbn[c] - muh*ga;
    float gl = glow[c]*rsl, bl = blow[c] - mul*gl;
    float4 h = *(const float4*)(hp + (size_t)p);
    float4 l = *(const float4*)(lp + (size_t)p);
    float4 o;
    o.x = mishf(h.x*ga + bh + l.x*gl + bl);
    o.y = mishf(h.y*ga + bh + l.y*gl + bl);
    o.z = mishf(h.z*ga + bh + l.z*gl + bl);
    o.w = mishf(h.w*ga + bh + l.w*gl + bl);
    *(float4*)(r + (size_t)p) = o;
}

// ---------------- K5: 3x3 conv 16->16 pad1; blockIdx.z = b*2 + co-half ----------------
// co-half h computes output channels h*8..h*8+7 == GN group h.
__global__ __launch_bounds__(128) void k_ref(const float* __restrict__ rin,
                                             const float* __restrict__ WTr,
                                             float* __restrict__ outp,
                                             float* __restrict__ stat) {
    __shared__ float buf[2][TSZ];
    int tid = threadIdx.x;
    int bz = blockIdx.z; int b = bz >> 1; int h = bz & 1;
    int x0 = blockIdx.x * 64, y0 = blockIdx.y * 8;
    int tx = tid & 15, ty = tid >> 4;
    float acc[8][4];
    #pragma unroll
    for (int c = 0; c < 8; ++c) { acc[c][0]=acc[c][1]=acc[c][2]=acc[c][3]=0.f; }
    const float* wb = WTr + h*1152;

    stage_rows(rin, buf[0], b, 0, y0, x0, tid, 1, 11);
    for (int ci = 0; ci < 16; ++ci) {
        __syncthreads();
        if (ci < 15) stage_rows(rin, buf[(ci+1)&1], b, ci+1, y0, x0, tid, 1, 11);
        conv8<1>(buf[ci&1], wb + ci*72, tx, ty, acc);
    }

    float s = 0.f, q = 0.f;
    float* ob = outp + (size_t)(b*16 + h*8)*HW + (y0+ty)*WW + x0 + tx*4;
    #pragma unroll
    for (int c = 0; c < 8; ++c) {
        *(float4*)(ob + (size_t)c*HW) = make_float4(acc[c][0],acc[c][1],acc[c][2],acc[c][3]);
        #pragma unroll
        for (int j = 0; j < 4; ++j) { s += acc[c][j]; q += acc[c][j]*acc[c][j]; }
    }
    #pragma unroll
    for (int o = 32; o > 0; o >>= 1) { s += __shfl_down(s,o); q += __shfl_down(q,o); }
    if ((tid & 63) == 0) {
        atomicAdd(&stat[b*4 + h*2], s); atomicAdd(&stat[b*4 + h*2 + 1], q);
    }
}

// ---------------- K6: GN-apply + mish + 1x1 seg conv 16->1 ----------------
__global__ __launch_bounds__(256) void k_seg(const float* __restrict__ rp,
                                             const float* __restrict__ gref, const float* __restrict__ bref,
                                             const float* __restrict__ wseg, const float* __restrict__ sr,
                                             float* __restrict__ seg) {
    int i4 = blockIdx.x * 256 + threadIdx.x;    // 196608 total
    int b = i4 >> 12; int off = (i4 & 4095) << 2;
    const float* pb = rp + (size_t)b*16*HW + off;
    float ax=0.f, ay=0.f, az=0.f, aw=0.f;
    #pragma unroll
    for (int c = 0; c < 16; ++c) {
        int gi = b*4 + (c>>3)*2;
        float mu = sr[gi] * (1.f/131072.f);
        float var = sr[gi+1]*(1.f/131072.f) - mu*mu;
        float rs = rsqrtf(var + EPS);
        float ga = gref[c]*rs, bb = bref[c] - mu*ga;
        float wv = wseg[c];
        float4 v = *(const float4*)(pb + (size_t)c*HW);
        ax += wv*mishf(v.x*ga + bb);
        ay += wv*mishf(v.y*ga + bb);
        az += wv*mishf(v.z*ga + bb);
        aw += wv*mishf(v.w*ga + bb);
    }
    *(float4*)(seg + (size_t)b*HW + off) = make_float4(ax,ay,az,aw);
}

// ---------------- K7: bilinear x4 upsample + sigmoid ----------------
__global__ __launch_bounds__(256) void k_up(const float* __restrict__ seg, float* __restrict__ out) {
    int i4 = blockIdx.x * 256 + threadIdx.x;    // 3,145,728 total
    int b = i4 / (512*128);
    int rem = i4 - b*(512*128);
    int y = rem >> 7; int k = rem & 127;
    const float* sp = seg + (size_t)b * HW;
    float fy = fminf(fmaxf(0.25f*y - 0.375f, 0.f), 127.f);
    int y0 = min((int)fy, 126);
    float wy = fy - (float)y0;
    const float* r0 = sp + y0*WW;
    const float* r1 = r0 + WW;
    float res[4];
    #pragma unroll
    for (int j = 0; j < 4; ++j) {
        int x = k*4 + j;
        float fx = fminf(fmaxf(0.25f*x - 0.375f, 0.f), 127.f);
        int x0 = min((int)fx, 126);
        float wx = fx - (float)x0;
        float v0 = r0[x0]*(1.f-wx) + r0[x0+1]*wx;
        float v1 = r1[x0]*(1.f-wx) + r1[x0+1]*wx;
        float v = v0*(1.f-wy) + v1*wy;
        res[j] = 1.f/(1.f + __expf(-v));
    }
    *(float4*)(out + (size_t)i4*4) = make_float4(res[0],res[1],res[2],res[3]);
}

extern "C" void kernel_launch(void* const* d_in, const int* in_sizes, int n_in,
                              void* d_out, int out_size, void* d_ws, size_t ws_size,
                              hipStream_t stream) {
    const float* low  = (const float*)d_in[0];
    const float* high = (const float*)d_in[1];
    const float* Wc0  = (const float*)d_in[2];
    const float* Wc1  = (const float*)d_in[3];
    const float* Wc2  = (const float*)d_in[4];
    const float* gbn  = (const float*)d_in[5];
    const float* bbn  = (const float*)d_in[6];
    const float* Wlow = (const float*)d_in[7];
    const float* glow = (const float*)d_in[8];
    const float* blow = (const float*)d_in[9];
    const float* Wref = (const float*)d_in[10];
    const float* gref = (const float*)d_in[11];
    const float* bref = (const float*)d_in[12];
    const float* Wseg = (const float*)d_in[13];

    float* ws = (float*)d_ws;
    float* A  = ws;                        // in0, later r
    float* Bb = ws + (size_t)SZ;           // high_pre, later ref_pre
    float* C  = ws + 2*(size_t)SZ;         // low_pre
    float* D  = ws + 3*(size_t)SZ;         // seg (48*16384)
    float* ST = D + (size_t)48*HW;         // stats: 480 floats (zeroed each launch)
    float* WTb = ST + 480;                 // 1152 floats: branch weights [br][ci][kyx][co8]
    float* WTr = WTb + 1152;               // 2304 floats: ref weights [h][ci][kyx][co8]

    hipMemsetAsync(ST, 0, 480*sizeof(float), stream);

    k_c0    <<<768, 256, 0, stream>>>(high, Wc0, Wc1, Wc2, Wref, WTb, WTr, A);
    k_branch<<<dim3(2,16,96), 128, 0, stream>>>(A, WTb, Bb, ST);
    k_low   <<<768, 256, 0, stream>>>(low, Wlow, C, ST + 96);
    k_fuse  <<<12288, 256, 0, stream>>>(Bb, C, gbn, bbn, glow, blow, ST, ST + 96, A);
    k_ref   <<<dim3(2,16,96), 128, 0, stream>>>(A, WTr, Bb, ST + 288);
    k_seg   <<<768, 256, 0, stream>>>(Bb, gref, bref, Wseg, ST + 288, D);
    k_up    <<<12288, 256, 0, stream>>>(D, (float*)d_out);
}

// Round 4
// 475.857 us; speedup vs baseline: 1.2557x; 1.1846x over previous
//
#include <hip/hip_runtime.h>
#include <math.h>

#define BATCH 48
#define HH 128
#define WW 128
#define HW (128*128)
#define SZ (48*16*HW)          // 12,582,912 floats per 16-ch feature map
#define EPS 1e-5f

// mish(x) = x*tanh(softplus(x)) = x * t(t+2)/(t(t+2)+2), t = e^x  (exact identity)
__device__ __forceinline__ float mishf(float v) {
    float t = __expf(fminf(v, 20.f));      // clamp: for v>20 result == v to fp32 precision
    float u = t * (t + 2.f);
    return v * (u / (u + 2.f));
}

// ---------------- K1: 1x1 conv 32->16 (high_fea -> in0) + weight transposes ----------------
__global__ __launch_bounds__(256) void k_c0(const float* __restrict__ x,
                                            const float* __restrict__ W,
                                            const float* __restrict__ Wc1,
                                            const float* __restrict__ Wc2,
                                            const float* __restrict__ Wref,
                                            float* __restrict__ WTb,   // 1152 floats
                                            float* __restrict__ WTr,   // 2304 floats
                                            float* __restrict__ out) {
    __shared__ float w[16*32];
    int tid = threadIdx.x;
    for (int i = tid; i < 512; i += 256) w[i] = W[i];
    if (blockIdx.x == 0) {
        for (int i = tid; i < 576; i += 256) {
            int co = i & 7; int t = i >> 3; int kyx = t % 9; int ci = t / 9;
            WTb[(ci*9 + kyx)*8 + co]       = Wc1[(co*8 + ci)*9 + kyx];
            WTb[576 + (ci*9 + kyx)*8 + co] = Wc2[(co*8 + ci)*9 + kyx];
        }
        for (int i = tid; i < 2304; i += 256) {
            int co = i & 7; int t = i >> 3; int kyx = t % 9; int cih = t / 9;  // 0..31
            int ci = cih & 15; int h = cih >> 4;
            WTr[((h*16 + ci)*9 + kyx)*8 + co] = Wref[((h*8 + co)*16 + ci)*9 + kyx];
        }
    }
    __syncthreads();
    int g = blockIdx.x * 256 + tid;          // 4-pixel group index
    int b = g >> 12;                         // 4096 groups per batch
    int off = (g & 4095) << 2;
    const float* xb = x + (size_t)b * 32 * HW + off;
    float acc[16][4];
    #pragma unroll
    for (int c = 0; c < 16; ++c) { acc[c][0]=acc[c][1]=acc[c][2]=acc[c][3]=0.f; }
    #pragma unroll 4
    for (int ci = 0; ci < 32; ++ci) {
        float4 xv = *(const float4*)(xb + (size_t)ci * HW);
        #pragma unroll
        for (int co = 0; co < 16; ++co) {
            float wv = w[co*32 + ci];
            acc[co][0] += wv*xv.x; acc[co][1] += wv*xv.y;
            acc[co][2] += wv*xv.z; acc[co][3] += wv*xv.w;
        }
    }
    float* ob = out + (size_t)b * 16 * HW + off;
    #pragma unroll
    for (int co = 0; co < 16; ++co)
        *(float4*)(ob + (size_t)co * HW) = make_float4(acc[co][0],acc[co][1],acc[co][2],acc[co][3]);
}

// ------------- shared helpers for tiled 3x3 convs -------------
// Tile: 64 wide x 8 tall outputs per 128-thread block.
// LDS window per channel: rows R0..R1 of a 12x68 window; row r = global y0-2+r, col c = x0-2+c.
#define TROWS 12
#define TCOLS 68
#define TSZ (TROWS*TCOLS)

// Load one channel's window rows into registers (no LDS yet).
template<int R0, int R1, int NR>
__device__ __forceinline__ void load_rows_reg(const float* __restrict__ p,
                                              int y0, int x0, int tid, float (&v)[NR]) {
    #pragma unroll
    for (int k = 0; k < NR; ++k) {
        int i = tid + R0*TCOLS + k*128;
        float val = 0.f;
        if (i < R1*TCOLS) {
            int r = i / TCOLS, cc = i - r*TCOLS;
            int gy = y0 - 2 + r, gx = x0 - 2 + cc;
            if ((unsigned)gy < 128u && (unsigned)gx < 128u) val = p[gy*WW + gx];
        }
        v[k] = val;
    }
}

template<int R0, int R1, int NR>
__device__ __forceinline__ void write_rows_reg(float* __restrict__ dst, int tid, const float (&v)[NR]) {
    #pragma unroll
    for (int k = 0; k < NR; ++k) {
        int i = tid + R0*TCOLS + k*128;
        if (i < R1*TCOLS) dst[i] = v[k];
    }
}

// 8 output channels, dilation D. Weights wt: 72 floats [kyx][co8], wave-uniform -> SGPRs.
template<int D>
__device__ __forceinline__ void conv8(const float* __restrict__ sb, const float* __restrict__ wt,
                                      int tx, int ty, float (&acc)[8][4]) {
    #pragma unroll
    for (int ky = 0; ky < 3; ++ky) {
        const float* rp = sb + (ty + 2 + D*(ky-1))*TCOLS + tx*4;
        float4 lo = *(const float4*)rp;
        float4 hi = *(const float4*)(rp + 4);
        float u[8] = {lo.x,lo.y,lo.z,lo.w,hi.x,hi.y,hi.z,hi.w};
        #pragma unroll
        for (int kx = 0; kx < 3; ++kx) {
            const float* wp = wt + (ky*3 + kx)*8;
            float w0 = wp[0], w1 = wp[1], w2 = wp[2], w3 = wp[3];
            float w4 = wp[4], w5 = wp[5], w6 = wp[6], w7 = wp[7];
            #pragma unroll
            for (int j = 0; j < 4; ++j) {
                float v = u[2 - D + D*kx + j];
                acc[0][j] += w0*v; acc[1][j] += w1*v;
                acc[2][j] += w2*v; acc[3][j] += w3*v;
                acc[4][j] += w4*v; acc[5][j] += w5*v;
                acc[6][j] += w6*v; acc[7][j] += w7*v;
            }
        }
    }
}

// ---------------- K2: dual-branch 3x3; blockIdx.z = b*2 + branch ----------------
// branch 0: dil1, in ch 0-7, out ch 0-7; branch 1: dil2, in ch 8-15, out ch 8-15.
// Register-pipelined staging: loads for next channel pair issue BEFORE this pair's convs.
__global__ __launch_bounds__(128) void k_branch(const float* __restrict__ in0,
                                                const float* __restrict__ WTb,
                                                float* __restrict__ outp,
                                                float* __restrict__ stat) {
    __shared__ float buf[4][TSZ];
    int tid = threadIdx.x;
    int bz = blockIdx.z; int b = bz >> 1; int br = bz & 1;
    int x0 = blockIdx.x * 64, y0 = blockIdx.y * 8;
    int tx = tid & 15, ty = tid >> 4;
    float acc[8][4];
    #pragma unroll
    for (int c = 0; c < 8; ++c) { acc[c][0]=acc[c][1]=acc[c][2]=acc[c][3]=0.f; }
    int c0 = br*8;
    const float* base = in0 + (size_t)(b*16 + c0) * HW;
    const float* wb = WTb + br*576;

    if (br == 0) {
        float rg[2][6];
        load_rows_reg<1,11,6>(base,      y0, x0, tid, rg[0]);
        load_rows_reg<1,11,6>(base + HW, y0, x0, tid, rg[1]);
        write_rows_reg<1,11,6>(buf[0], tid, rg[0]);
        write_rows_reg<1,11,6>(buf[1], tid, rg[1]);
        __syncthreads();
        for (int i = 0; i < 8; i += 2) {
            float ng[2][6];
            if (i + 2 < 8) {
                load_rows_reg<1,11,6>(base + (size_t)(i+2)*HW, y0, x0, tid, ng[0]);
                load_rows_reg<1,11,6>(base + (size_t)(i+3)*HW, y0, x0, tid, ng[1]);
            }
            conv8<1>(buf[i&3],     wb + i*72,     tx, ty, acc);
            conv8<1>(buf[(i+1)&3], wb + (i+1)*72, tx, ty, acc);
            if (i + 2 < 8) {
                write_rows_reg<1,11,6>(buf[(i+2)&3], tid, ng[0]);
                write_rows_reg<1,11,6>(buf[(i+3)&3], tid, ng[1]);
                __syncthreads();
            }
        }
    } else {
        float rg[2][7];
        load_rows_reg<0,12,7>(base,      y0, x0, tid, rg[0]);
        load_rows_reg<0,12,7>(base + HW, y0, x0, tid, rg[1]);
        write_rows_reg<0,12,7>(buf[0], tid, rg[0]);
        write_rows_reg<0,12,7>(buf[1], tid, rg[1]);
        __syncthreads();
        for (int i = 0; i < 8; i += 2) {
            float ng[2][7];
            if (i + 2 < 8) {
                load_rows_reg<0,12,7>(base + (size_t)(i+2)*HW, y0, x0, tid, ng[0]);
                load_rows_reg<0,12,7>(base + (size_t)(i+3)*HW, y0, x0, tid, ng[1]);
            }
            conv8<2>(buf[i&3],     wb + i*72,     tx, ty, acc);
            conv8<2>(buf[(i+1)&3], wb + (i+1)*72, tx, ty, acc);
            if (i + 2 < 8) {
                write_rows_reg<0,12,7>(buf[(i+2)&3], tid, ng[0]);
                write_rows_reg<0,12,7>(buf[(i+3)&3], tid, ng[1]);
                __syncthreads();
            }
        }
    }

    float s = 0.f, q = 0.f;
    float* ob = outp + (size_t)(b*16 + c0)*HW + (y0+ty)*WW + x0 + tx*4;
    #pragma unroll
    for (int c = 0; c < 8; ++c) {
        *(float4*)(ob + (size_t)c*HW) = make_float4(acc[c][0],acc[c][1],acc[c][2],acc[c][3]);
        #pragma unroll
        for (int j = 0; j < 4; ++j) { s += acc[c][j]; q += acc[c][j]*acc[c][j]; }
    }
    #pragma unroll
    for (int o = 32; o > 0; o >>= 1) { s += __shfl_down(s,o); q += __shfl_down(q,o); }
    if ((tid & 63) == 0) { atomicAdd(&stat[b*2], s); atomicAdd(&stat[b*2+1], q); }
}

// ---------------- K3: 1x1 conv 24->16 (low) + GN(groups=2) stats ----------------
__global__ __launch_bounds__(256) void k_low(const float* __restrict__ x,
                                             const float* __restrict__ W,
                                             float* __restrict__ outp,
                                             float* __restrict__ stat) {
    __shared__ float w[16*24];
    int tid = threadIdx.x;
    for (int i = tid; i < 384; i += 256) w[i] = W[i];
    __syncthreads();
    int g = blockIdx.x * 256 + tid;
    int b = g >> 12; int off = (g & 4095) << 2;
    const float* xb = x + (size_t)b * 24 * HW + off;
    float acc[16][4];
    #pragma unroll
    for (int c = 0; c < 16; ++c) { acc[c][0]=acc[c][1]=acc[c][2]=acc[c][3]=0.f; }
    #pragma unroll 4
    for (int ci = 0; ci < 24; ++ci) {
        float4 xv = *(const float4*)(xb + (size_t)ci * HW);
        #pragma unroll
        for (int co = 0; co < 16; ++co) {
            float wv = w[co*24 + ci];
            acc[co][0] += wv*xv.x; acc[co][1] += wv*xv.y;
            acc[co][2] += wv*xv.z; acc[co][3] += wv*xv.w;
        }
    }
    float* ob = outp + (size_t)b * 16 * HW + off;
    float s0=0.f,q0=0.f,s1=0.f,q1=0.f;
    #pragma unroll
    for (int co = 0; co < 16; ++co) {
        *(float4*)(ob + (size_t)co * HW) = make_float4(acc[co][0],acc[co][1],acc[co][2],acc[co][3]);
        #pragma unroll
        for (int j = 0; j < 4; ++j) {
            if (co < 8) { s0 += acc[co][j]; q0 += acc[co][j]*acc[co][j]; }
            else        { s1 += acc[co][j]; q1 += acc[co][j]*acc[co][j]; }
        }
    }
    #pragma unroll
    for (int o = 32; o > 0; o >>= 1) {
        s0 += __shfl_down(s0,o); q0 += __shfl_down(q0,o);
        s1 += __shfl_down(s1,o); q1 += __shfl_down(q1,o);
    }
    if ((tid & 63) == 0) {
        atomicAdd(&stat[b*4+0], s0); atomicAdd(&stat[b*4+1], q0);
        atomicAdd(&stat[b*4+2], s1); atomicAdd(&stat[b*4+3], q1);
    }
}

// ---------------- K4: GN-apply (high & low) + add + mish ----------------
__global__ __launch_bounds__(256) void k_fuse(const float* __restrict__ hp, const float* __restrict__ lp,
                                              const float* __restrict__ gbn, const float* __restrict__ bbn,
                                              const float* __restrict__ glow, const float* __restrict__ blow,
                                              const float* __restrict__ sh, const float* __restrict__ sl,
                                              float* __restrict__ r) {
    int i4 = blockIdx.x * 256 + threadIdx.x;
    int p = i4 << 2;
    int b = p >> 18;                 // / (16*HW)
    int rem = p & 262143;
    int c = rem >> 14;               // / HW
    float muh = sh[b*2] * (1.f/262144.f);
    float varh = sh[b*2+1]*(1.f/262144.f) - muh*muh;
    float rsh = rsqrtf(varh + EPS);
    int gi = b*4 + (c>>3)*2;
    float mul = sl[gi] * (1.f/131072.f);
    float varl = sl[gi+1]*(1.f/131072.f) - mul*mul;
    float rsl = rsqrtf(varl + EPS);
    float ga = gbn[c]*rsh, bh = bbn[c] - muh*ga;
    float gl = glow[c]*rsl, bl = blow[c] - mul*gl;
    float4 h = *(const float4*)(hp + (size_t)p);
    float4 l = *(const float4*)(lp + (size_t)p);
    float4 o;
    o.x = mishf(h.x*ga + bh + l.x*gl + bl);
    o.y = mishf(h.y*ga + bh + l.y*gl + bl);
    o.z = mishf(h.z*ga + bh + l.z*gl + bl);
    o.w = mishf(h.w*ga + bh + l.w*gl + bl);
    *(float4*)(r + (size_t)p) = o;
}

// ---------------- K5: 3x3 conv 16->16 pad1; blockIdx.z = b*2 + co-half ----------------
__global__ __launch_bounds__(128) void k_ref(const float* __restrict__ rin,
                                             const float* __restrict__ WTr,
                                             float* __restrict__ outp,
                                             float* __restrict__ stat) {
    __shared__ float buf[4][TSZ];
    int tid = threadIdx.x;
    int bz = blockIdx.z; int b = bz >> 1; int h = bz & 1;
    int x0 = blockIdx.x * 64, y0 = blockIdx.y * 8;
    int tx = tid & 15, ty = tid >> 4;
    float acc[8][4];
    #pragma unroll
    for (int c = 0; c < 8; ++c) { acc[c][0]=acc[c][1]=acc[c][2]=acc[c][3]=0.f; }
    const float* base = rin + (size_t)b*16*HW;
    const float* wb = WTr + h*1152;

    float rg[2][6];
    load_rows_reg<1,11,6>(base,      y0, x0, tid, rg[0]);
    load_rows_reg<1,11,6>(base + HW, y0, x0, tid, rg[1]);
    write_rows_reg<1,11,6>(buf[0], tid, rg[0]);
    write_rows_reg<1,11,6>(buf[1], tid, rg[1]);
    __syncthreads();
    for (int i = 0; i < 16; i += 2) {
        float ng[2][6];
        if (i + 2 < 16) {
            load_rows_reg<1,11,6>(base + (size_t)(i+2)*HW, y0, x0, tid, ng[0]);
            load_rows_reg<1,11,6>(base + (size_t)(i+3)*HW, y0, x0, tid, ng[1]);
        }
        conv8<1>(buf[i&3],     wb + i*72,     tx, ty, acc);
        conv8<1>(buf[(i+1)&3], wb + (i+1)*72, tx, ty, acc);
        if (i + 2 < 16) {
            write_rows_reg<1,11,6>(buf[(i+2)&3], tid, ng[0]);
            write_rows_reg<1,11,6>(buf[(i+3)&3], tid, ng[1]);
            __syncthreads();
        }
    }

    float s = 0.f, q = 0.f;
    float* ob = outp + (size_t)(b*16 + h*8)*HW + (y0+ty)*WW + x0 + tx*4;
    #pragma unroll
    for (int c = 0; c < 8; ++c) {
        *(float4*)(ob + (size_t)c*HW) = make_float4(acc[c][0],acc[c][1],acc[c][2],acc[c][3]);
        #pragma unroll
        for (int j = 0; j < 4; ++j) { s += acc[c][j]; q += acc[c][j]*acc[c][j]; }
    }
    #pragma unroll
    for (int o = 32; o > 0; o >>= 1) { s += __shfl_down(s,o); q += __shfl_down(q,o); }
    if ((tid & 63) == 0) {
        atomicAdd(&stat[b*4 + h*2], s); atomicAdd(&stat[b*4 + h*2 + 1], q);
    }
}

// ---------------- K6: GN-apply + mish + 1x1 seg conv 16->1 ----------------
__global__ __launch_bounds__(256) void k_seg(const float* __restrict__ rp,
                                             const float* __restrict__ gref, const float* __restrict__ bref,
                                             const float* __restrict__ wseg, const float* __restrict__ sr,
                                             float* __restrict__ seg) {
    int i4 = blockIdx.x * 256 + threadIdx.x;    // 196608 total
    int b = i4 >> 12; int off = (i4 & 4095) << 2;
    const float* pb = rp + (size_t)b*16*HW + off;
    float ax=0.f, ay=0.f, az=0.f, aw=0.f;
    #pragma unroll
    for (int c = 0; c < 16; ++c) {
        int gi = b*4 + (c>>3)*2;
        float mu = sr[gi] * (1.f/131072.f);
        float var = sr[gi+1]*(1.f/131072.f) - mu*mu;
        float rs = rsqrtf(var + EPS);
        float ga = gref[c]*rs, bb = bref[c] - mu*ga;
        float wv = wseg[c];
        float4 v = *(const float4*)(pb + (size_t)c*HW);
        ax += wv*mishf(v.x*ga + bb);
        ay += wv*mishf(v.y*ga + bb);
        az += wv*mishf(v.z*ga + bb);
        aw += wv*mishf(v.w*ga + bb);
    }
    *(float4*)(seg + (size_t)b*HW + off) = make_float4(ax,ay,az,aw);
}

// ---------------- K7: bilinear x4 upsample + sigmoid ----------------
__global__ __launch_bounds__(256) void k_up(const float* __restrict__ seg, float* __restrict__ out) {
    int i4 = blockIdx.x * 256 + threadIdx.x;    // 3,145,728 total
    int b = i4 / (512*128);
    int rem = i4 - b*(512*128);
    int y = rem >> 7; int k = rem & 127;
    const float* sp = seg + (size_t)b * HW;
    float fy = fminf(fmaxf(0.25f*y - 0.375f, 0.f), 127.f);
    int y0 = min((int)fy, 126);
    float wy = fy - (float)y0;
    const float* r0 = sp + y0*WW;
    const float* r1 = r0 + WW;
    float res[4];
    #pragma unroll
    for (int j = 0; j < 4; ++j) {
        int x = k*4 + j;
        float fx = fminf(fmaxf(0.25f*x - 0.375f, 0.f), 127.f);
        int x0 = min((int)fx, 126);
        float wx = fx - (float)x0;
        float v0 = r0[x0]*(1.f-wx) + r0[x0+1]*wx;
        float v1 = r1[x0]*(1.f-wx) + r1[x0+1]*wx;
        float v = v0*(1.f-wy) + v1*wy;
        res[j] = 1.f/(1.f + __expf(-v));
    }
    *(float4*)(out + (size_t)i4*4) = make_float4(res[0],res[1],res[2],res[3]);
}

extern "C" void kernel_launch(void* const* d_in, const int* in_sizes, int n_in,
                              void* d_out, int out_size, void* d_ws, size_t ws_size,
                              hipStream_t stream) {
    const float* low  = (const float*)d_in[0];
    const float* high = (const float*)d_in[1];
    const float* Wc0  = (const float*)d_in[2];
    const float* Wc1  = (const float*)d_in[3];
    const float* Wc2  = (const float*)d_in[4];
    const float* gbn  = (const float*)d_in[5];
    const float* bbn  = (const float*)d_in[6];
    const float* Wlow = (const float*)d_in[7];
    const float* glow = (const float*)d_in[8];
    const float* blow = (const float*)d_in[9];
    const float* Wref = (const float*)d_in[10];
    const float* gref = (const float*)d_in[11];
    const float* bref = (const float*)d_in[12];
    const float* Wseg = (const float*)d_in[13];

    float* ws = (float*)d_ws;
    float* A  = ws;                        // in0, later r
    float* Bb = ws + (size_t)SZ;           // high_pre, later ref_pre
    float* C  = ws + 2*(size_t)SZ;         // low_pre
    float* D  = ws + 3*(size_t)SZ;         // seg (48*16384)
    float* ST = D + (size_t)48*HW;         // stats: 480 floats (zeroed each launch)
    float* WTb = ST + 480;                 // 1152 floats: branch weights [br][ci][kyx][co8]
    float* WTr = WTb + 1152;               // 2304 floats: ref weights [h][ci][kyx][co8]

    hipMemsetAsync(ST, 0, 480*sizeof(float), stream);

    k_c0    <<<768, 256, 0, stream>>>(high, Wc0, Wc1, Wc2, Wref, WTb, WTr, A);
    k_branch<<<dim3(2,16,96), 128, 0, stream>>>(A, WTb, Bb, ST);
    k_low   <<<768, 256, 0, stream>>>(low, Wlow, C, ST + 96);
    k_fuse  <<<12288, 256, 0, stream>>>(Bb, C, gbn, bbn, glow, blow, ST, ST + 96, A);
    k_ref   <<<dim3(2,16,96), 128, 0, stream>>>(A, WTr, Bb, ST + 288);
    k_seg   <<<768, 256, 0, stream>>>(Bb, gref, bref, Wseg, ST + 288, D);
    k_up    <<<12288, 256, 0, stream>>>(D, (float*)d_out);
}